// Round 1
// baseline (500.995 us; speedup 1.0000x reference)
//
#include <hip/hip_runtime.h>
#include <hip/hip_bf16.h>
#include <stdint.h>

// LayerNormLSTM: T=512, B=64, I=1024, H=1024
// M = T*B = 32768 rows, N = 4*H = 4096, K = 1024.
// Reference degenerates (h0=c0=0, no scan):
//   h2h_vec = LN(bh; g_h2h, b_h2h)                         (constant 4096-vec; Wh unused)
//   y       = x @ Wi^T                                      (big GEMM)
//   p       = g_i2h * LNrow(y + bi) + (b_i2h + h2h_vec)
//   f,o     = sigmoid(p[H:2H]), sigmoid(p[2H:3H]); g = tanh(p[3H:])
//   c       = (1-f)*g ;  cn = LN_H(c; g_cell, b_cell) ;  h = o * tanh(cn)
// out = [h (T,B,H) ; h[-1] (B,H)]

#define MROWS 32768L
#define NCOLS 4096
#define KDIM  1024

typedef __bf16 bf16x8 __attribute__((ext_vector_type(8)));
typedef __bf16 bf16x4 __attribute__((ext_vector_type(4)));
typedef float  f32x4  __attribute__((ext_vector_type(4)));

__device__ float g_Cvec[4096];   // b_i2h + h2h_vec (recomputed every launch)

__device__ __forceinline__ void gload16(char* lds, const char* g) {
  __builtin_amdgcn_global_load_lds(
      (const __attribute__((address_space(1))) char*)g,
      (__attribute__((address_space(3))) char*)lds, 16, 0, 0);
}

__device__ __forceinline__ void block_reduce2(float& a, float& b, float* red, int tid) {
#pragma unroll
  for (int m = 32; m > 0; m >>= 1) {
    a += __shfl_xor(a, m, 64);
    b += __shfl_xor(b, m, 64);
  }
  const int lane = tid & 63, wid = tid >> 6;
  if (lane == 0) { red[wid] = a; red[4 + wid] = b; }
  __syncthreads();
  a = red[0] + red[1] + red[2] + red[3];
  b = red[4] + red[5] + red[6] + red[7];
  __syncthreads();  // safe reuse of red[]
}

// ---------------- cast f32 -> bf16 (vectorized) ----------------
__global__ __launch_bounds__(256) void cast_kernel(const float4* __restrict__ in,
                                                   bf16x4* __restrict__ out, int n4) {
  int i = blockIdx.x * 256 + threadIdx.x;
  const int stride = gridDim.x * 256;
  for (; i < n4; i += stride) {
    const float4 v = in[i];
    bf16x4 o = { (__bf16)v.x, (__bf16)v.y, (__bf16)v.z, (__bf16)v.w };
    out[i] = o;
  }
}

// ---------------- prep: Cvec = b_i2h + LN(bh)*g_h2h + b_h2h ----------------
__global__ __launch_bounds__(256) void prep_kernel(const float* __restrict__ bh,
                                                   const float* __restrict__ b_i2h,
                                                   const float* __restrict__ g_h2h,
                                                   const float* __restrict__ b_h2h) {
  __shared__ float red[8];
  const int tid = threadIdx.x;
  float v[16];
  float s = 0.f, ss = 0.f;
#pragma unroll
  for (int u = 0; u < 16; ++u) {
    v[u] = bh[tid + u * 256];
    s += v[u]; ss += v[u] * v[u];
  }
  block_reduce2(s, ss, red, tid);
  const float mu  = s * (1.f / 4096.f);
  const float var = (ss - 4096.f * mu * mu) * (1.f / 4095.f);   // ddof=1
  const float rs  = rsqrtf(var + 1e-6f);
#pragma unroll
  for (int u = 0; u < 16; ++u) {
    const int g = tid + u * 256;
    g_Cvec[g] = b_i2h[g] + g_h2h[g] * ((v[u] - mu) * rs) + b_h2h[g];
  }
}

// ---------------- GEMM: Y[m][n] = sum_k A[m][k]*B[n][k]  (bf16 in, bf16 out) ----
// m97 structure: 128x128 tile, BK=64, 4 waves, global_load_lds w=16, 2-barrier loop.
__global__ __launch_bounds__(256) void gemm_kernel(const __bf16* __restrict__ A,
                                                   const __bf16* __restrict__ B,
                                                   __bf16* __restrict__ Y, long r0) {
  __shared__ __align__(16) __bf16 As[128 * 64];
  __shared__ __align__(16) __bf16 Bs[128 * 64];
  const int tid  = threadIdx.x;
  const int lane = tid & 63;
  const int wid  = tid >> 6;
  const int wm   = wid >> 1;       // 0..1
  const int wn   = wid & 1;        // 0..1
  const int bid  = blockIdx.x;
  const long m0  = (long)(bid >> 5) * 128;   // local row tile (within chunk)
  const long n0  = (long)(bid & 31) * 128;

  // staging: byteoff(c) = c*4096 + tid*16  ->  row = c*32 + tid/8, inrow = (tid&7)*16
  const int srow  = tid >> 3;
  const int sbyte = (tid & 7) << 4;
  const char* Ag = (const char*)(A + (r0 + m0) * KDIM) + (long)srow * 2048 + sbyte;
  const char* Bg = (const char*)(B + n0 * KDIM) + (long)srow * 2048 + sbyte;
  char* Al = (char*)As + tid * 16;
  char* Bl = (char*)Bs + tid * 16;

  f32x4 acc[4][4];
  const f32x4 z = {0.f, 0.f, 0.f, 0.f};
#pragma unroll
  for (int i = 0; i < 4; ++i)
#pragma unroll
    for (int j = 0; j < 4; ++j) acc[i][j] = z;

  const int fr = lane & 15;           // frag row (A) / col (B)
  const int fk = (lane >> 4) << 3;    // k offset 0,8,16,24
  const __bf16* ArdBase = &As[(wm * 64 + fr) * 64 + fk];
  const __bf16* BrdBase = &Bs[(wn * 64 + fr) * 64 + fk];

  for (int kt = 0; kt < KDIM / 64; ++kt) {
    const long koff = (long)kt * 128;  // bytes along K
#pragma unroll
    for (int c = 0; c < 4; ++c) {
      gload16(Al + c * 4096, Ag + (long)c * 32 * 2048 + koff);
      gload16(Bl + c * 4096, Bg + (long)c * 32 * 2048 + koff);
    }
    __syncthreads();
#pragma unroll
    for (int s = 0; s < 2; ++s) {
      bf16x8 a[4], b[4];
#pragma unroll
      for (int i = 0; i < 4; ++i) a[i] = *(const bf16x8*)(ArdBase + i * 16 * 64 + s * 32);
#pragma unroll
      for (int j = 0; j < 4; ++j) b[j] = *(const bf16x8*)(BrdBase + j * 16 * 64 + s * 32);
#pragma unroll
      for (int i = 0; i < 4; ++i)
#pragma unroll
        for (int j = 0; j < 4; ++j)
          acc[i][j] = __builtin_amdgcn_mfma_f32_16x16x32_bf16(a[i], b[j], acc[i][j], 0, 0, 0);
    }
    __syncthreads();
  }

  // epilogue: store bf16 Y (local rows within chunk)
  const long orow0 = m0 + wm * 64 + ((lane >> 4) << 2);
  const long ocol0 = n0 + wn * 64 + fr;
#pragma unroll
  for (int i = 0; i < 4; ++i)
#pragma unroll
    for (int j = 0; j < 4; ++j)
#pragma unroll
      for (int r = 0; r < 4; ++r)
        Y[(orow0 + i * 16 + r) * NCOLS + ocol0 + j * 16] = (__bf16)acc[i][j][r];
}

// ---------------- pass 2: row LN + gates + cell LN + output ----------------
__global__ __launch_bounds__(256) void pass2_kernel(const __bf16* __restrict__ Yw,
                                                    const float* __restrict__ bi,
                                                    const float* __restrict__ g_i2h,
                                                    const float* __restrict__ g_cell,
                                                    const float* __restrict__ b_cell,
                                                    float* __restrict__ out, long r0) {
  __shared__ float p0[4096];
  __shared__ float red[8];
  const int tid  = threadIdx.x;
  const long row = r0 + blockIdx.x;           // global row (t*64 + b)
  const bf16x8* yv = (const bf16x8*)(Yw + (long)blockIdx.x * NCOLS);

  // phase 1: p = y + bi (fp32), stash in LDS, accumulate stats over 4096
  float s = 0.f, ss = 0.f;
#pragma unroll
  for (int it = 0; it < 2; ++it) {
    const int ch = tid + it * 256;            // 8-elem chunk id, 0..511
    const bf16x8 v = yv[ch];
    const float4 b0 = ((const float4*)bi)[ch * 2];
    const float4 b1 = ((const float4*)bi)[ch * 2 + 1];
    float p[8];
    p[0] = (float)v[0] + b0.x;  p[1] = (float)v[1] + b0.y;
    p[2] = (float)v[2] + b0.z;  p[3] = (float)v[3] + b0.w;
    p[4] = (float)v[4] + b1.x;  p[5] = (float)v[5] + b1.y;
    p[6] = (float)v[6] + b1.z;  p[7] = (float)v[7] + b1.w;
#pragma unroll
    for (int u = 0; u < 8; ++u) {
      p0[ch * 8 + u] = p[u];
      s += p[u];
      ss += p[u] * p[u];
    }
  }
  block_reduce2(s, ss, red, tid);             // also fences p0 writes
  const float mu  = s * (1.f / 4096.f);
  const float var = (ss - 4096.f * mu * mu) * (1.f / 4095.f);   // ddof=1
  const float rs  = rsqrtf(var + 1e-6f);

  // phase 2: gates + cell accumulation (j = tid + u*256)
  float cc[4], oo[4];
  float s2 = 0.f, ss2 = 0.f;
#pragma unroll
  for (int u = 0; u < 4; ++u) {
    const int j = tid + u * 256;
    const float pf = g_i2h[1024 + j] * ((p0[1024 + j] - mu) * rs) + g_Cvec[1024 + j];
    const float po = g_i2h[2048 + j] * ((p0[2048 + j] - mu) * rs) + g_Cvec[2048 + j];
    const float pg = g_i2h[3072 + j] * ((p0[3072 + j] - mu) * rs) + g_Cvec[3072 + j];
    const float f  = 1.f / (1.f + __expf(-pf));
    oo[u] = 1.f / (1.f + __expf(-po));
    const float e2 = __expf(2.f * pg);
    const float gt = (e2 - 1.f) / (e2 + 1.f);   // tanh
    cc[u] = (1.f - f) * gt;                     // c0 = 0
    s2 += cc[u]; ss2 += cc[u] * cc[u];
  }
  block_reduce2(s2, ss2, red, tid);
  const float mu2  = s2 * (1.f / 1024.f);
  const float var2 = (ss2 - 1024.f * mu2 * mu2) * (1.f / 1023.f);  // ddof=1
  const float rs2  = rsqrtf(var2 + 1e-6f);

  const long obase = row * 1024;
#pragma unroll
  for (int u = 0; u < 4; ++u) {
    const int j = tid + u * 256;
    const float cn = g_cell[j] * ((cc[u] - mu2) * rs2) + b_cell[j];
    const float e2 = __expf(2.f * cn);
    const float th = (e2 - 1.f) / (e2 + 1.f);
    const float h  = oo[u] * th;
    out[obase + j] = h;
    if (row >= MROWS - 64)                       // t == T-1
      out[MROWS * 1024 + ((row - (MROWS - 64)) << 10) + j] = h;
  }
}

extern "C" void kernel_launch(void* const* d_in, const int* in_sizes, int n_in,
                              void* d_out, int out_size, void* d_ws, size_t ws_size,
                              hipStream_t stream) {
  (void)in_sizes; (void)n_in; (void)out_size;
  const float* x      = (const float*)d_in[0];
  const float* Wi     = (const float*)d_in[1];
  const float* bi     = (const float*)d_in[2];
  // d_in[3] = Wh : unused (h0 == 0)
  const float* bh     = (const float*)d_in[4];
  const float* g_i2h  = (const float*)d_in[5];
  const float* b_i2h  = (const float*)d_in[6];
  const float* g_h2h  = (const float*)d_in[7];
  const float* b_h2h  = (const float*)d_in[8];
  const float* g_cell = (const float*)d_in[9];
  const float* b_cell = (const float*)d_in[10];
  float* out = (float*)d_out;

  // Scratch carved from d_out (fully overwritten by pass2 afterwards):
  //   [0, 64MB)    x as bf16
  //   [64MB, 72MB) Wi as bf16
  __bf16* xb = (__bf16*)d_out;
  __bf16* wb = (__bf16*)((char*)d_out + 67108864);
  __bf16* y  = (__bf16*)d_ws;   // Y intermediate, up to 256 MB (chunked if ws smaller)

  cast_kernel<<<2048, 256, 0, stream>>>((const float4*)x, (bf16x4*)xb, 33554432 / 4);
  cast_kernel<<<1024, 256, 0, stream>>>((const float4*)Wi, (bf16x4*)wb, 4194304 / 4);
  prep_kernel<<<1, 256, 0, stream>>>(bh, b_i2h, g_h2h, b_h2h);

  // chunk over M if the workspace can't hold the full 32768x4096 bf16 Y
  long max_rows = (long)(ws_size / (NCOLS * 2)) & ~127L;
  if (max_rows > MROWS) max_rows = MROWS;
  if (max_rows < 128)   max_rows = 128;   // assume ws >= 1 MB
  for (long rbase = 0; rbase < MROWS; rbase += max_rows) {
    const long rows = (MROWS - rbase < max_rows) ? (MROWS - rbase) : max_rows;
    gemm_kernel<<<dim3((rows / 128) * 32), 256, 0, stream>>>(xb, wb, y, rbase);
    pass2_kernel<<<dim3(rows), 256, 0, stream>>>(y, bi, g_i2h, g_cell, b_cell, out, rbase);
  }
}